// Round 1
// baseline (363.780 us; speedup 1.0000x reference)
//
#include <hip/hip_runtime.h>

typedef __attribute__((ext_vector_type(8))) short short8;
typedef __attribute__((ext_vector_type(4))) float floatx4;

#define IN_C 128
#define OUT_C 256
#define NB 32
#define HW 56
#define S_PER_N (HW * HW)          // 3136
#define M_TOTAL (NB * S_PER_N)     // 100352
#define PH 58                      // padded height
#define PW 66                      // padded width
#define XN_ELEMS (NB * PH * PW * IN_C)   // 15,679,488
#define WT_ELEMS (9 * OUT_C * IN_C)      // 294,912

__device__ __forceinline__ unsigned short f2bf(float f) {
    unsigned int u = __builtin_bit_cast(unsigned int, f);
    u = (u + 0x7FFFu + ((u >> 16) & 1u)) >> 16;   // RNE
    return (unsigned short)u;
}

// x (N,C,56,56) fp32  ->  xn (N,58,66,C) bf16 with zero halo baked in.
// One block per (n, ihp) padded row.
__global__ void xform_x(const float* __restrict__ x, unsigned short* __restrict__ xn) {
    const int ihp = blockIdx.x;          // 0..57
    const int n   = blockIdx.y;          // 0..31
    const int tid = threadIdx.x;         // 256 threads
    unsigned int* __restrict__ row32 =
        (unsigned int*)(xn + (size_t)(n * PH + ihp) * PW * IN_C);
    const int WORDS = PW * IN_C / 2;     // 4224 uint32 per row

    if (ihp == 0 || ihp == PH - 1) {
        for (int i = tid; i < WORDS; i += 256) row32[i] = 0u;
        return;
    }
    const int ih = ihp - 1;
    __shared__ float lds[IN_C][HW + 1];  // [ic][iw], +1 pad
    const float* __restrict__ xrow = x + (size_t)n * IN_C * S_PER_N + (size_t)ih * HW;
    for (int i = tid; i < IN_C * HW; i += 256) {
        int ic = i / HW, iw = i % HW;    // consecutive tid -> consecutive iw (coalesced)
        lds[ic][iw] = xrow[(size_t)ic * S_PER_N + iw];
    }
    __syncthreads();
    for (int wi = tid; wi < WORDS; wi += 256) {
        int pix = wi >> 6;               // 0..65
        int ic  = (wi & 63) * 2;
        unsigned int val = 0u;
        if (pix >= 1 && pix <= HW) {
            int iw = pix - 1;
            unsigned int lo = f2bf(lds[ic][iw]);
            unsigned int hi = f2bf(lds[ic + 1][iw]);
            val = (hi << 16) | lo;
        }
        row32[wi] = val;
    }
}

// w (256,128,3,3) fp32 -> wt[khw][oc][ic] bf16
__global__ void xform_w(const float* __restrict__ w, unsigned short* __restrict__ wt) {
    const int idx = blockIdx.x * 256 + threadIdx.x;   // 0..294911, grid exact
    const int ic  = idx & 127;
    const int oc  = (idx >> 7) & 255;
    const int khw = idx >> 15;
    wt[idx] = f2bf(w[(oc * IN_C + ic) * 9 + khw]);
}

// Implicit GEMM: C[oc][s] = sum_k wt[k][oc] * act[k][s]
// A operand = weights (M=oc), B operand = activations (N=s).
// Block: 256 thr = 4 waves; block tile 128 oc x 128 s; wave tile 64x64 (4x4 MFMA).
__global__ void __launch_bounds__(256)
conv_mfma(const unsigned short* __restrict__ xn,
          const unsigned short* __restrict__ wt,
          float* __restrict__ out) {
    const int tid  = threadIdx.x;
    const int lane = tid & 63;
    const int wv   = tid >> 6;        // 0..3
    const int l15  = lane & 15;
    const int quad = lane >> 4;       // 0..3

    const int bx      = blockIdx.x;
    const int tile_oc = bx & 1;       // 2 oc tiles of 128
    const int tile_m  = bx >> 1;      // 784 spatial tiles of 128

    const int s0  = tile_m * 128 + (wv & 1) * 64;   // wave spatial base
    const int oc0 = tile_oc * 128 + (wv >> 1) * 64; // wave oc base

    // B (activation) pointers: one per 16-wide s subtile; loop-invariant.
    const unsigned short* bptr[4];
#pragma unroll
    for (int j = 0; j < 4; ++j) {
        int s_glob = s0 + j * 16 + l15;
        int n  = s_glob / S_PER_N;
        int r  = s_glob % S_PER_N;
        int oh = r / HW;
        int ow = r % HW;
        bptr[j] = xn + ((size_t)((n * PH + oh) * PW + ow) * IN_C + quad * 8);
    }
    // A (weight) pointers: one per 16-wide oc subtile; loop-invariant.
    const unsigned short* aptr[4];
#pragma unroll
    for (int i = 0; i < 4; ++i) {
        aptr[i] = wt + ((size_t)(oc0 + i * 16 + l15) * IN_C + quad * 8);
    }

    floatx4 acc[4][4];
#pragma unroll
    for (int i = 0; i < 4; ++i)
#pragma unroll
        for (int j = 0; j < 4; ++j) acc[i][j] = (floatx4){0.f, 0.f, 0.f, 0.f};

#pragma unroll
    for (int khw = 0; khw < 9; ++khw) {
        const int kh = khw / 3, kw = khw % 3;
        const int xo = (kh * PW + kw) * IN_C;     // activation k-group offset
        const int wo = khw * OUT_C * IN_C;        // weight k-group offset
#pragma unroll
        for (int st = 0; st < 4; ++st) {
            const int ic0 = st * 32;
            short8 a[4], b[4];
#pragma unroll
            for (int j = 0; j < 4; ++j)
                b[j] = *(const short8*)(bptr[j] + xo + ic0);
#pragma unroll
            for (int i = 0; i < 4; ++i)
                a[i] = *(const short8*)(aptr[i] + wo + ic0);
#pragma unroll
            for (int i = 0; i < 4; ++i)
#pragma unroll
                for (int j = 0; j < 4; ++j)
                    acc[i][j] = __builtin_amdgcn_mfma_f32_16x16x32_bf16(
                        a[i], b[j], acc[i][j], 0, 0, 0);
        }
    }

    // Epilogue: C/D layout col=lane&15 (s), row=quad*4+reg (oc).
#pragma unroll
    for (int j = 0; j < 4; ++j) {
        int s_glob = s0 + j * 16 + l15;
        int n = s_glob / S_PER_N;
        int s = s_glob % S_PER_N;
        float* obase = out + (size_t)n * OUT_C * S_PER_N + s;
#pragma unroll
        for (int i = 0; i < 4; ++i) {
            int oc = oc0 + i * 16 + quad * 4;
#pragma unroll
            for (int r = 0; r < 4; ++r)
                obase[(size_t)(oc + r) * S_PER_N] = acc[i][j][r];
        }
    }
}

extern "C" void kernel_launch(void* const* d_in, const int* in_sizes, int n_in,
                              void* d_out, int out_size, void* d_ws, size_t ws_size,
                              hipStream_t stream) {
    const float* x = (const float*)d_in[0];
    const float* w = (const float*)d_in[1];
    float* out = (float*)d_out;

    unsigned short* xn = (unsigned short*)d_ws;      // 31,358,976 B
    unsigned short* wt = xn + XN_ELEMS;              // 589,824 B (offset 256B-aligned)

    dim3 gx(PH, NB);
    xform_x<<<gx, 256, 0, stream>>>(x, xn);
    xform_w<<<WT_ELEMS / 256, 256, 0, stream>>>(w, wt);
    conv_mfma<<<(M_TOTAL / 128) * 2, 256, 0, stream>>>(xn, wt, out);
}

// Round 2
// 223.255 us; speedup vs baseline: 1.6294x; 1.6294x over previous
//
#include <hip/hip_runtime.h>

typedef __attribute__((ext_vector_type(8))) short short8;
typedef __attribute__((ext_vector_type(4))) float floatx4;

#define IN_C 128
#define OUT_C 256
#define NB 32
#define HW 56
#define S_PER_N (HW * HW)          // 3136
#define M_TOTAL (NB * S_PER_N)     // 100352
#define PH 58                      // padded height
#define PW 66                      // padded width
#define XN_ELEMS (NB * PH * PW * IN_C)   // 15,679,488
#define WT_ELEMS (9 * OUT_C * IN_C)      // 294,912

__device__ __forceinline__ unsigned short f2bf(float f) {
    unsigned int u = __builtin_bit_cast(unsigned int, f);
    u = (u + 0x7FFFu + ((u >> 16) & 1u)) >> 16;   // RNE
    return (unsigned short)u;
}

// Direct global->LDS DMA, 16B per lane. LDS dest must be base + lane*16.
__device__ __forceinline__ void gld_lds16(const unsigned short* g, unsigned short* l) {
    __builtin_amdgcn_global_load_lds(
        (const __attribute__((address_space(1))) unsigned int*)g,
        (__attribute__((address_space(3))) unsigned int*)l, 16, 0, 0);
}

// x (N,C,56,56) fp32  ->  xn (N,58,66,C) bf16 with zero halo baked in.
__global__ void xform_x(const float* __restrict__ x, unsigned short* __restrict__ xn) {
    const int ihp = blockIdx.x;          // 0..57
    const int n   = blockIdx.y;          // 0..31
    const int tid = threadIdx.x;         // 256 threads
    unsigned int* __restrict__ row32 =
        (unsigned int*)(xn + (size_t)(n * PH + ihp) * PW * IN_C);
    const int WORDS = PW * IN_C / 2;     // 4224 uint32 per row

    if (ihp == 0 || ihp == PH - 1) {
        for (int i = tid; i < WORDS; i += 256) row32[i] = 0u;
        return;
    }
    const int ih = ihp - 1;
    __shared__ float lds[IN_C][HW + 1];  // [ic][iw], +1 pad
    const float* __restrict__ xrow = x + (size_t)n * IN_C * S_PER_N + (size_t)ih * HW;
    // float4 reads: 56 = 14 * 4, all 16B-aligned (224B row pitch, 12544B ic pitch)
    for (int i = tid; i < IN_C * 14; i += 256) {
        int ic = i / 14, iw4 = (i % 14) * 4;
        float4 v = *(const float4*)(xrow + (size_t)ic * S_PER_N + iw4);
        lds[ic][iw4 + 0] = v.x;
        lds[ic][iw4 + 1] = v.y;
        lds[ic][iw4 + 2] = v.z;
        lds[ic][iw4 + 3] = v.w;
    }
    __syncthreads();
    for (int wi = tid; wi < WORDS; wi += 256) {
        int pix = wi >> 6;               // 0..65
        int ic  = (wi & 63) * 2;
        unsigned int val = 0u;
        if (pix >= 1 && pix <= HW) {
            int iw = pix - 1;
            unsigned int lo = f2bf(lds[ic][iw]);
            unsigned int hi = f2bf(lds[ic + 1][iw]);
            val = (hi << 16) | lo;
        }
        row32[wi] = val;
    }
}

// w (256,128,3,3) fp32 -> wt[khw][oc][ic] bf16
__global__ void xform_w(const float* __restrict__ w, unsigned short* __restrict__ wt) {
    const int idx = blockIdx.x * 256 + threadIdx.x;   // grid exact
    const int ic  = idx & 127;
    const int oc  = (idx >> 7) & 255;
    const int khw = idx >> 15;
    wt[idx] = f2bf(w[(oc * IN_C + ic) * 9 + khw]);
}

// Implicit GEMM, m97 structure: LDS-staged tiles via global_load_lds(16B),
// 2-barrier K-loop, ds_read_b128 fragments, 16x16x32 bf16 MFMA.
// Block 256 thr = 4 waves; tile 128 oc x 128 s; wave 64x64 (4x4 MFMA); BK=32.
__global__ void __launch_bounds__(256)
conv_mfma(const unsigned short* __restrict__ xn,
          const unsigned short* __restrict__ wt,
          float* __restrict__ out) {
    const int tid  = threadIdx.x;
    const int lane = tid & 63;
    const int wv   = tid >> 6;        // 0..3
    const int l15  = lane & 15;
    const int quad = lane >> 4;       // 0..3

    const int bx      = blockIdx.x;
    const int tile_oc = bx & 1;       // 2 oc tiles of 128
    const int tile_m  = bx >> 1;      // 784 spatial tiles of 128

    const int s_blk  = tile_m * 128;
    const int oc_blk = tile_oc * 128;
    const int s0  = s_blk + (wv & 1) * 64;    // wave spatial base
    const int oc0 = oc_blk + (wv >> 1) * 64;  // wave oc base

    __shared__ unsigned short A_lds[128 * 32];   // [oc_local][ic32] 8 KB
    __shared__ unsigned short B_lds[128 * 32];   // [s_local][ic32]  8 KB

    // ---- staging addresses (thread t moves 16B per issue; 2 issues per tile) ----
    const int srow = tid >> 2;          // 0..63
    const int sic  = (tid & 3) * 8;     // ic sub-offset (elements)

    // A: wt[khw][oc][ic], row = 128 elems. issue q covers oc_local = q*64 + srow.
    const unsigned short* a_g0 = wt + (size_t)(oc_blk + srow) * IN_C + sic;
    const unsigned short* a_g1 = a_g0 + 64 * IN_C;

    // B: xn pixel base for s_local = q*64 + srow.
    const unsigned short* b_g[2];
#pragma unroll
    for (int q = 0; q < 2; ++q) {
        int sg = s_blk + q * 64 + srow;
        int n  = sg / S_PER_N;
        int r  = sg % S_PER_N;
        int oh = r / HW, ow = r % HW;
        b_g[q] = xn + (size_t)((n * PH + oh) * PW + ow) * IN_C + sic;
    }
    // LDS dests: issue q at byte q*4096 + tid*16  -> elem q*2048 + tid*8
    unsigned short* a_l0 = A_lds + tid * 8;
    unsigned short* a_l1 = A_lds + 2048 + tid * 8;
    unsigned short* b_l0 = B_lds + tid * 8;
    unsigned short* b_l1 = B_lds + 2048 + tid * 8;

    // ---- fragment read offsets (elements) ----
    int afo[4], bfo[4];
#pragma unroll
    for (int i = 0; i < 4; ++i)
        afo[i] = ((wv >> 1) * 64 + i * 16 + l15) * 32 + quad * 8;
#pragma unroll
    for (int j = 0; j < 4; ++j)
        bfo[j] = ((wv & 1) * 64 + j * 16 + l15) * 32 + quad * 8;

    floatx4 acc[4][4];
#pragma unroll
    for (int i = 0; i < 4; ++i)
#pragma unroll
        for (int j = 0; j < 4; ++j) acc[i][j] = (floatx4){0.f, 0.f, 0.f, 0.f};

#pragma unroll
    for (int khw = 0; khw < 9; ++khw) {
        const int xo = ((khw / 3) * PW + (khw % 3)) * IN_C;  // activation k-offset
        const int wo = khw * OUT_C * IN_C;                   // weight k-offset
#pragma unroll
        for (int st = 0; st < 4; ++st) {
            const int ic0 = st * 32;
            __syncthreads();                      // previous tile consumed
            gld_lds16(a_g0 + wo + ic0, a_l0);
            gld_lds16(a_g1 + wo + ic0, a_l1);
            gld_lds16(b_g[0] + xo + ic0, b_l0);
            gld_lds16(b_g[1] + xo + ic0, b_l1);
            __syncthreads();                      // tile loaded (vmcnt drained)

            short8 a[4], b[4];
#pragma unroll
            for (int i = 0; i < 4; ++i) a[i] = *(const short8*)(A_lds + afo[i]);
#pragma unroll
            for (int j = 0; j < 4; ++j) b[j] = *(const short8*)(B_lds + bfo[j]);
#pragma unroll
            for (int i = 0; i < 4; ++i)
#pragma unroll
                for (int j = 0; j < 4; ++j)
                    acc[i][j] = __builtin_amdgcn_mfma_f32_16x16x32_bf16(
                        a[i], b[j], acc[i][j], 0, 0, 0);
        }
    }

    // Epilogue: C/D layout col=lane&15 (s), row=quad*4+reg (oc).
#pragma unroll
    for (int j = 0; j < 4; ++j) {
        int s_glob = s0 + j * 16 + l15;
        int n = s_glob / S_PER_N;
        int s = s_glob % S_PER_N;
        float* obase = out + (size_t)n * OUT_C * S_PER_N + s;
#pragma unroll
        for (int i = 0; i < 4; ++i) {
            int oc = oc0 + i * 16 + quad * 4;
#pragma unroll
            for (int r = 0; r < 4; ++r)
                obase[(size_t)(oc + r) * S_PER_N] = acc[i][j][r];
        }
    }
}

extern "C" void kernel_launch(void* const* d_in, const int* in_sizes, int n_in,
                              void* d_out, int out_size, void* d_ws, size_t ws_size,
                              hipStream_t stream) {
    const float* x = (const float*)d_in[0];
    const float* w = (const float*)d_in[1];
    float* out = (float*)d_out;

    unsigned short* xn = (unsigned short*)d_ws;      // 31,358,976 B
    unsigned short* wt = xn + XN_ELEMS;              // 589,824 B

    dim3 gx(PH, NB);
    xform_x<<<gx, 256, 0, stream>>>(x, xn);
    xform_w<<<WT_ELEMS / 256, 256, 0, stream>>>(w, wt);
    conv_mfma<<<(M_TOTAL / 128) * 2, 256, 0, stream>>>(xn, wt, out);
}

// Round 3
// 217.419 us; speedup vs baseline: 1.6732x; 1.0268x over previous
//
#include <hip/hip_runtime.h>

typedef __attribute__((ext_vector_type(8))) short short8;
typedef __attribute__((ext_vector_type(4))) float floatx4;

#define IN_C 128
#define OUT_C 256
#define NB 32
#define HW 56
#define S_PER_N (HW * HW)          // 3136
#define M_TOTAL (NB * S_PER_N)     // 100352
#define PH 58                      // padded height
#define PW 66                      // padded width
#define XN_ELEMS (NB * PH * PW * IN_C)   // 15,679,488
#define WT_ELEMS (9 * OUT_C * IN_C)      // 294,912

__device__ __forceinline__ unsigned short f2bf(float f) {
    unsigned int u = __builtin_bit_cast(unsigned int, f);
    u = (u + 0x7FFFu + ((u >> 16) & 1u)) >> 16;   // RNE
    return (unsigned short)u;
}

// Direct global->LDS DMA, 16B per lane. LDS dest must be base + lane*16.
__device__ __forceinline__ void gld_lds16(const unsigned short* g, unsigned short* l) {
    __builtin_amdgcn_global_load_lds(
        (const __attribute__((address_space(1))) unsigned int*)g,
        (__attribute__((address_space(3))) unsigned int*)l, 16, 0, 0);
}

// x (N,C,56,56) fp32  ->  xn (N,58,66,C) bf16 with zero halo baked in.
// LDS transposed to [iw][ic] u16 so the write loop does conflict-free u32 reads.
__global__ void xform_x(const float* __restrict__ x, unsigned short* __restrict__ xn) {
    const int ihp = blockIdx.x;          // 0..57
    const int n   = blockIdx.y;          // 0..31
    const int tid = threadIdx.x;         // 256 threads
    unsigned int* __restrict__ row32 =
        (unsigned int*)(xn + (size_t)(n * PH + ihp) * PW * IN_C);
    const int WORDS = PW * IN_C / 2;     // 4224 uint32 per row

    if (ihp == 0 || ihp == PH - 1) {
        for (int i = tid; i < WORDS; i += 256) row32[i] = 0u;
        return;
    }
    const int ih = ihp - 1;
    __shared__ unsigned short lds2[HW][IN_C];   // [iw][ic] bf16, 14336 B
    const float* __restrict__ xrow = x + (size_t)n * IN_C * S_PER_N + (size_t)ih * HW;
    for (int i = tid; i < IN_C * 14; i += 256) {   // 7 iters: float4 per (ic, iw4)
        int ic = i / 14, iw4 = (i % 14) * 4;
        float4 v = *(const float4*)(xrow + (size_t)ic * S_PER_N + iw4);
        lds2[iw4 + 0][ic] = f2bf(v.x);
        lds2[iw4 + 1][ic] = f2bf(v.y);
        lds2[iw4 + 2][ic] = f2bf(v.z);
        lds2[iw4 + 3][ic] = f2bf(v.w);
    }
    __syncthreads();
    for (int wi = tid; wi < WORDS; wi += 256) {
        int pix = wi >> 6;               // 0..65
        int icw = wi & 63;               // ic pair index
        unsigned int val = 0u;
        if (pix >= 1 && pix <= HW)
            val = *(const unsigned int*)&lds2[pix - 1][icw * 2];
        row32[wi] = val;
    }
}

// w (256,128,3,3) fp32 -> wt[khw][oc][ic] bf16
__global__ void xform_w(const float* __restrict__ w, unsigned short* __restrict__ wt) {
    const int idx = blockIdx.x * 256 + threadIdx.x;   // grid exact
    const int ic  = idx & 127;
    const int oc  = (idx >> 7) & 255;
    const int khw = idx >> 15;
    wt[idx] = f2bf(w[(oc * IN_C + ic) * 9 + khw]);
}

// Implicit GEMM: LDS-staged via global_load_lds(16B), BK=64 (18 barrier-pairs),
// block 128 oc x 128 s, 4 waves, wave 64x64 (4x4 of 16x16x32 bf16 MFMA).
// __launch_bounds__(256,3): pin 3 waves/SIMD -> 3 blocks/CU (LDS 32KB, regs<=170).
__global__ void __launch_bounds__(256, 3)
conv_mfma(const unsigned short* __restrict__ xn,
          const unsigned short* __restrict__ wt,
          float* __restrict__ out) {
    const int tid  = threadIdx.x;
    const int lane = tid & 63;
    const int wv   = tid >> 6;        // 0..3
    const int l15  = lane & 15;
    const int quad = lane >> 4;       // 0..3

    const int bx      = blockIdx.x;
    const int tile_oc = bx & 1;       // 2 oc tiles of 128
    const int tile_m  = bx >> 1;      // 784 spatial tiles of 128

    const int s_blk  = tile_m * 128;
    const int oc_blk = tile_oc * 128;
    const int s0  = s_blk + (wv & 1) * 64;    // wave spatial base
    const int oc0 = oc_blk + (wv >> 1) * 64;  // wave oc base

    __shared__ unsigned short A_lds[128 * 64];   // [oc_local][ic64] 16 KB
    __shared__ unsigned short B_lds[128 * 64];   // [s_local][ic64]  16 KB

    // ---- staging addresses: thread covers (row = q*32 + tid>>3, ic8 = (tid&7)*8) ----
    const int srow = tid >> 3;          // 0..31
    const int sic  = (tid & 7) * 8;     // 0..56

    const unsigned short* a_g[4];
    const unsigned short* b_g[4];
#pragma unroll
    for (int q = 0; q < 4; ++q) {
        int row = q * 32 + srow;
        a_g[q] = wt + (size_t)(oc_blk + row) * IN_C + sic;
        int sg = s_blk + row;
        int n  = sg / S_PER_N;
        int r  = sg % S_PER_N;
        int oh = r / HW, ow = r % HW;
        b_g[q] = xn + (size_t)((n * PH + oh) * PW + ow) * IN_C + sic;
    }
    // LDS dests: issue q at elem q*2048 + tid*8 (byte q*4096 + tid*16)
    unsigned short* a_l = A_lds + tid * 8;
    unsigned short* b_l = B_lds + tid * 8;

    // ---- fragment read offsets (elements), row stride 64 ----
    int afo[4], bfo[4];
#pragma unroll
    for (int i = 0; i < 4; ++i)
        afo[i] = ((wv >> 1) * 64 + i * 16 + l15) * 64 + quad * 8;
#pragma unroll
    for (int j = 0; j < 4; ++j)
        bfo[j] = ((wv & 1) * 64 + j * 16 + l15) * 64 + quad * 8;

    floatx4 acc[4][4];
#pragma unroll
    for (int i = 0; i < 4; ++i)
#pragma unroll
        for (int j = 0; j < 4; ++j) acc[i][j] = (floatx4){0.f, 0.f, 0.f, 0.f};

#pragma unroll
    for (int khw = 0; khw < 9; ++khw) {
        const int xo = ((khw / 3) * PW + (khw % 3)) * IN_C;  // activation k-offset
        const int wo = khw * OUT_C * IN_C;                   // weight k-offset
#pragma unroll
        for (int h = 0; h < 2; ++h) {
            const int ic0 = h * 64;
            __syncthreads();                      // previous tile consumed
#pragma unroll
            for (int q = 0; q < 4; ++q) {
                gld_lds16(a_g[q] + wo + ic0, a_l + q * 2048);
                gld_lds16(b_g[q] + xo + ic0, b_l + q * 2048);
            }
            __syncthreads();                      // tile loaded (vmcnt drained)

#pragma unroll
            for (int kk = 0; kk < 2; ++kk) {
                const int ko = kk * 32;
                short8 a[4], b[4];
#pragma unroll
                for (int i = 0; i < 4; ++i) a[i] = *(const short8*)(A_lds + afo[i] + ko);
#pragma unroll
                for (int j = 0; j < 4; ++j) b[j] = *(const short8*)(B_lds + bfo[j] + ko);
#pragma unroll
                for (int i = 0; i < 4; ++i)
#pragma unroll
                    for (int j = 0; j < 4; ++j)
                        acc[i][j] = __builtin_amdgcn_mfma_f32_16x16x32_bf16(
                            a[i], b[j], acc[i][j], 0, 0, 0);
            }
        }
    }

    // Epilogue: C/D layout col=lane&15 (s), row=quad*4+reg (oc).
#pragma unroll
    for (int j = 0; j < 4; ++j) {
        int s_glob = s0 + j * 16 + l15;
        int n = s_glob / S_PER_N;
        int s = s_glob % S_PER_N;
        float* obase = out + (size_t)n * OUT_C * S_PER_N + s;
#pragma unroll
        for (int i = 0; i < 4; ++i) {
            int oc = oc0 + i * 16 + quad * 4;
#pragma unroll
            for (int r = 0; r < 4; ++r)
                obase[(size_t)(oc + r) * S_PER_N] = acc[i][j][r];
        }
    }
}

extern "C" void kernel_launch(void* const* d_in, const int* in_sizes, int n_in,
                              void* d_out, int out_size, void* d_ws, size_t ws_size,
                              hipStream_t stream) {
    const float* x = (const float*)d_in[0];
    const float* w = (const float*)d_in[1];
    float* out = (float*)d_out;

    unsigned short* xn = (unsigned short*)d_ws;      // 31,358,976 B
    unsigned short* wt = xn + XN_ELEMS;              // 589,824 B

    dim3 gx(PH, NB);
    xform_x<<<gx, 256, 0, stream>>>(x, xn);
    xform_w<<<WT_ELEMS / 256, 256, 0, stream>>>(w, wt);
    conv_mfma<<<(M_TOTAL / 128) * 2, 256, 0, stream>>>(xn, wt, out);
}